// Round 2
// 435.779 us; speedup vs baseline: 1.0193x; 1.0193x over previous
//
#include <hip/hip_runtime.h>
#include <cstdint>
#include <cstddef>

// Problem dims (fixed by setup_inputs)
#define B_  8
#define S_  4096
#define D_  1024
#define H_  1024
#define M_  (B_*S_)          // 32768 GEMM rows
#define NT_ 2048             // interleaved N (k,p pairs at 16-col granularity)
#define NC_ 64               // scan chunks
#define L_  (S_/NC_)         // 64 steps per chunk

typedef __bf16 bf16x8 __attribute__((ext_vector_type(8)));
typedef float  f32x4  __attribute__((ext_vector_type(4)));
typedef uint16_t u16x8 __attribute__((ext_vector_type(8)));

__device__ __forceinline__ uint16_t f2bf(float f) {
  union { float f; uint32_t u; } v; v.f = f;
  uint32_t u = v.u;
  u += 0x7FFFu + ((u >> 16) & 1u);   // RNE
  return (uint16_t)(u >> 16);
}
__device__ __forceinline__ float gfun(float x) {
  // g(x) = x+0.5 if x>=0 else sigmoid(x)
  return x >= 0.0f ? x + 0.5f
                   : __builtin_amdgcn_rcpf(1.0f + __expf(-x));
}
__device__ __forceinline__ void unpack_cv(uint32_t u, float& c, float& v) {
  union { uint32_t u; _Float16 h[2]; } p; p.u = u;
  c = (float)p.h[0]; v = (float)p.h[1];
}

// ---------------- fused fp32 -> bf16 convert for x, and Wz/Wh -> interleaved Wc --
// Wc row layout: group g (0..63): rows 32g..32g+15 = Wz rows 16g..16g+15,
//                                 rows 32g+16..32g+31 = Wh rows 16g..16g+15.
#define X8_  (M_ * D_ / 8)
#define W8_  (H_ * D_ / 8)
#define TOT8_ (X8_ + 2 * W8_)
__global__ __launch_bounds__(256) void cvt_all_kernel(
    const float* __restrict__ x, const float* __restrict__ Wz,
    const float* __restrict__ Wh, uint16_t* __restrict__ xb,
    uint16_t* __restrict__ Wc) {
  int stride = gridDim.x * 256;
  for (int u = blockIdx.x * 256 + threadIdx.x; u < TOT8_; u += stride) {
    const float* src; uint16_t* dst;
    if (u < X8_) {
      src = x + (size_t)u * 8; dst = xb + (size_t)u * 8;
    } else if (u < X8_ + W8_) {
      int v = u - X8_;
      int r = v >> 7, c = v & 127;
      int row = ((r >> 4) << 5) | (r & 15);
      src = Wz + (size_t)v * 8;
      dst = Wc + (size_t)row * D_ + c * 8;
    } else {
      int v = u - X8_ - W8_;
      int r = v >> 7, c = v & 127;
      int row = ((r >> 4) << 5) | 16 | (r & 15);
      src = Wh + (size_t)v * 8;
      dst = Wc + (size_t)row * D_ + c * 8;
    }
    float4 a = ((const float4*)src)[0], b = ((const float4*)src)[1];
    u16x8 o;
    o[0] = f2bf(a.x); o[1] = f2bf(a.y); o[2] = f2bf(a.z); o[3] = f2bf(a.w);
    o[4] = f2bf(b.x); o[5] = f2bf(b.y); o[6] = f2bf(b.z); o[7] = f2bf(b.w);
    *(u16x8*)dst = o;
  }
}

// ---------------- 256x256-tile 8-wave phase-split GEMM + activation epilogue ----
// C = A(32768x1024) * Wc^T(2048x1024). 8 waves as 2(M)x4(N); per-wave 128x64.
// 4 phases per K-tile (BK=64): phase p computes m-pair {2p,2p+1} (16 MFMA).
// Staging of tile t+1 spread 2 global_load_lds per phase into the other buffer;
// counted vmcnt(4)/vmcnt(2) waits (never 0 in main loop); raw s_barrier.
// LAST K-tile is PEELED: one vmcnt(0)+barrier drain, then compiler-ordered
// reads+MFMA (the counted-N arithmetic is wrong on a no-stage iteration:
// at t=15 p1 only 2 loads are outstanding so vmcnt(4) never gated A1/A3 —
// that race was the round-1 failure).
// Epilogue: tn even = k-frag, tn odd = p-frag for the SAME h columns (lane-local).
#define BK 64
__global__ __launch_bounds__(512, 2)
void fused_gemm_kernel(const uint16_t* __restrict__ A,
                       const uint16_t* __restrict__ Wc,
                       const float* __restrict__ bz,
                       const float* __restrict__ bh,
                       uint32_t* __restrict__ cv) {
  __shared__ __attribute__((aligned(16))) uint16_t sA[2][256 * BK];  // 2 x 32 KB
  __shared__ __attribute__((aligned(16))) uint16_t sB[2][256 * BK];  // 2 x 32 KB

  const int tid  = threadIdx.x;
  const int lane = tid & 63;
  const int wave = tid >> 6;
  const int wm = wave >> 2;        // 0..1  (M half)
  const int wn = wave & 3;         // 0..3  (N quarter)
  const int q  = lane >> 4;
  const int mn = lane & 15;

  // Bijective XCD swizzle: nwg=1024 (%8==0). Each XCD owns 16 contiguous
  // A row-panels (bx fastest within an XCD -> A panel stays L2-hot).
  const int bid  = blockIdx.x;
  const int tile = (bid & 7) * 128 + (bid >> 3);
  const int mTile = (tile >> 3) * 256;
  const int nTile = (tile & 7) * 256;

  // Staging addresses: load-unit L = 64 rows x 64 cols (8 KB = 512 thr x 16 B).
  // LDS dest is linear (tid*16 B); source col-unit pre-swizzled by cu^(r&7).
  const int rl = tid >> 3;         // 0..63 row within unit
  const int cu = tid & 7;          // 16B col-unit
  const int sw = cu ^ (rl & 7);
  const uint16_t* aSrc[4];
  const uint16_t* bSrc[4];
  #pragma unroll
  for (int L = 0; L < 4; L++) {
    aSrc[L] = A  + (size_t)(mTile + L * 64 + rl) * D_ + sw * 8;
    bSrc[L] = Wc + (size_t)(nTile + L * 64 + rl) * D_ + sw * 8;
  }
  const int ldsSlot = tid * 8;     // element offset inside the 4096-elem unit

  // Read-side bases (elements; row stride 64). r&7 == mn&7 for all fragments.
  const int swr = mn & 7;
  const int aBase = (wm * 128 + mn) * 64;
  const int bBase = (wn * 64  + mn) * 64;
  int koff[2];
  #pragma unroll
  for (int kk = 0; kk < 2; kk++) koff[kk] = ((kk * 4 + q) ^ swr) * 8;

#define STAGE_A(buf, kt, L)                                                    \
  __builtin_amdgcn_global_load_lds(                                            \
      (const __attribute__((address_space(1))) void*)(aSrc[L] + (kt) * BK),    \
      (__attribute__((address_space(3))) void*)&sA[buf][(L) * 4096 + ldsSlot], \
      16, 0, 0)
#define STAGE_B(buf, kt, L)                                                    \
  __builtin_amdgcn_global_load_lds(                                            \
      (const __attribute__((address_space(1))) void*)(bSrc[L] + (kt) * BK),    \
      (__attribute__((address_space(3))) void*)&sB[buf][(L) * 4096 + ldsSlot], \
      16, 0, 0)

  f32x4 acc[8][4] = {};

  // Prologue: tile 0 and tile 1, stream order A0,A2,B0,B1,B2,B3,A1,A3 each.
  STAGE_A(0, 0, 0); STAGE_A(0, 0, 2);
  STAGE_B(0, 0, 0); STAGE_B(0, 0, 1); STAGE_B(0, 0, 2); STAGE_B(0, 0, 3);
  STAGE_A(0, 0, 1); STAGE_A(0, 0, 3);
  STAGE_A(1, 1, 0); STAGE_A(1, 1, 2);
  STAGE_B(1, 1, 0); STAGE_B(1, 1, 1); STAGE_B(1, 1, 2); STAGE_B(1, 1, 3);
  STAGE_A(1, 1, 1); STAGE_A(1, 1, 3);
  asm volatile("s_waitcnt vmcnt(8)" ::: "memory");   // tile 0 fully landed
  __builtin_amdgcn_s_barrier();

  // Main loop over tiles 0..14 (tile 15 peeled).  Per-wave vmcnt ledger:
  //   entering p0: 2 outstanding (A1,A3 of tile t, issued at t-1 p3)
  //   p0 +2 (A0,A2 t+1) =4 | p1 +2 (B0,B1 t+1) =6, vmcnt(4) -> t's A1,A3 landed
  //   p2 +2 (B2,B3 t+1) =6 | p3 +2 (A1,A3 t+1) =8, vmcnt(2) -> t+1's first 6 landed
  // (t=0 issues nothing; its vmcnt(4)/vmcnt(2) gate tile1's prologue loads.)
  #pragma unroll 2
  for (int t = 0; t < D_ / BK - 1; ++t) {
    const int curb = t & 1, nxtb = curb ^ 1;
    const uint16_t* sAc = sA[curb];
    const uint16_t* sBc = sB[curb];
    const bool doStage = (t >= 1);
    const int kn = t + 1;

    bf16x8 bv[4][2];

    #pragma unroll
    for (int p = 0; p < 4; ++p) {
      // ds-load this phase's register subtile (data gated by earlier
      // vmcnt+barrier: first-6 halves by prev tile's p3, A1/A3 by this p1).
      if (p == 0) {
        #pragma unroll
        for (int tn = 0; tn < 4; tn++)
          #pragma unroll
          for (int kk = 0; kk < 2; kk++)
            bv[tn][kk] = *(const bf16x8*)&sBc[bBase + tn * 1024 + koff[kk]];
      }
      bf16x8 av[2][2];
      #pragma unroll
      for (int mi = 0; mi < 2; mi++)
        #pragma unroll
        for (int kk = 0; kk < 2; kk++)
          av[mi][kk] =
              *(const bf16x8*)&sAc[aBase + (2 * p + mi) * 1024 + koff[kk]];

      // Stage tile t+1 into the other buffer, consumption-lead order.
      if (doStage) {
        if (p == 0) { STAGE_A(nxtb, kn, 0); STAGE_A(nxtb, kn, 2); }
        if (p == 1) { STAGE_B(nxtb, kn, 0); STAGE_B(nxtb, kn, 1); }
        if (p == 2) { STAGE_B(nxtb, kn, 2); STAGE_B(nxtb, kn, 3); }
        if (p == 3) { STAGE_A(nxtb, kn, 1); STAGE_A(nxtb, kn, 3); }
      }

      __builtin_amdgcn_s_barrier();
      asm volatile("s_waitcnt lgkmcnt(0)" ::: "memory");
      __builtin_amdgcn_sched_barrier(0);
      __builtin_amdgcn_s_setprio(1);
      #pragma unroll
      for (int mi = 0; mi < 2; mi++)
        #pragma unroll
        for (int tn = 0; tn < 4; tn++)
          #pragma unroll
          for (int kk = 0; kk < 2; kk++)
            acc[2 * p + mi][tn] = __builtin_amdgcn_mfma_f32_16x16x32_bf16(
                av[mi][kk], bv[tn][kk], acc[2 * p + mi][tn], 0, 0, 0);
      __builtin_amdgcn_s_setprio(0);
      __builtin_amdgcn_sched_barrier(0);
      // Counted waits (never 0): p1 gates tile t's A1/A3 (read at p2);
      // p3 gates tile t+1's first 6 half-tiles (read at next p0).
      if (p == 1) asm volatile("s_waitcnt vmcnt(4)" ::: "memory");
      if (p == 3) asm volatile("s_waitcnt vmcnt(2)" ::: "memory");
      __builtin_amdgcn_s_barrier();
    }
  }
#undef STAGE_A
#undef STAGE_B

  // ---- Peeled tail: tile 15 (buffer 1). Drain the last 2 in-flight loads
  // (A1,A3 of tile 15), barrier so ALL waves' contributions have landed, then
  // plain reads + MFMA — no staging, no LDS writes, so no further sync needed.
  asm volatile("s_waitcnt vmcnt(0)" ::: "memory");
  __builtin_amdgcn_s_barrier();
  __builtin_amdgcn_sched_barrier(0);
  {
    const uint16_t* sAc = sA[1];
    const uint16_t* sBc = sB[1];
    bf16x8 bv[4][2];
    #pragma unroll
    for (int tn = 0; tn < 4; tn++)
      #pragma unroll
      for (int kk = 0; kk < 2; kk++)
        bv[tn][kk] = *(const bf16x8*)&sBc[bBase + tn * 1024 + koff[kk]];
    __builtin_amdgcn_s_setprio(1);
    #pragma unroll
    for (int m = 0; m < 8; m++) {
      bf16x8 av[2];
      #pragma unroll
      for (int kk = 0; kk < 2; kk++)
        av[kk] = *(const bf16x8*)&sAc[aBase + m * 1024 + koff[kk]];
      #pragma unroll
      for (int tn = 0; tn < 4; tn++)
        #pragma unroll
        for (int kk = 0; kk < 2; kk++)
          acc[m][tn] = __builtin_amdgcn_mfma_f32_16x16x32_bf16(
              av[kk], bv[tn][kk], acc[m][tn], 0, 0, 0);
    }
    __builtin_amdgcn_s_setprio(0);
  }

  // Epilogue: tn-pairs (0,1) and (2,3) hold (k,p) for the same 16 h-cols.
  // D layout: col=lane&15, row=q*4+i.
  #pragma unroll
  for (int tp = 0; tp < 2; ++tp) {
    const int ncol = nTile + wn * 64 + tp * 32;      // k-column base
    const int h = ((ncol >> 5) << 4) + mn;
    const float bzc = bz[h], bhc = bh[h];
    #pragma unroll
    for (int m = 0; m < 8; ++m) {
      const int row0 = mTile + wm * 128 + m * 16 + q * 4;
      #pragma unroll
      for (int i = 0; i < 4; ++i) {
        float kv = acc[m][2 * tp][i] + bzc;
        float pv = acc[m][2 * tp + 1][i] + bhc;
        float c = __builtin_amdgcn_rcpf(1.0f + __expf(kv));  // sigmoid(-k)
        float v = (1.0f - c) * gfun(pv);                      // sigmoid(k)*g(p)
        union { _Float16 h2[2]; uint32_t u; } pk;
        pk.h2[0] = (_Float16)c; pk.h2[1] = (_Float16)v;
        cv[(size_t)(row0 + i) * H_ + h] = pk.u;
      }
    }
  }
}

// ---------------- scan pass 1: per-chunk (C, V) composition ----------------
__global__ __launch_bounds__(256) void scan_chunk_kernel(
    const uint32_t* __restrict__ cv, float4* __restrict__ Cc,
    float4* __restrict__ Vc) {
  const int tid = threadIdx.x;                 // channels tid*4..tid*4+3
  const int nc = blockIdx.x, b = blockIdx.y;
  const uint4* cv4 = (const uint4*)cv;
  size_t base = (size_t)(b * S_ + nc * L_) * (H_ / 4) + tid;
  float C[4] = {1.f, 1.f, 1.f, 1.f};
  float V[4] = {0.f, 0.f, 0.f, 0.f};
  #pragma unroll 4
  for (int t = 0; t < L_; t++) {
    uint4 w = cv4[base + (size_t)t * (H_ / 4)];
    float c, v;
    unpack_cv(w.x, c, v); C[0] *= c; V[0] = c * V[0] + v;
    unpack_cv(w.y, c, v); C[1] *= c; V[1] = c * V[1] + v;
    unpack_cv(w.z, c, v); C[2] *= c; V[2] = c * V[2] + v;
    unpack_cv(w.w, c, v); C[3] *= c; V[3] = c * V[3] + v;
  }
  size_t o = (size_t)(b * NC_ + nc) * (H_ / 4) + tid;
  Cc[o] = (float4){C[0], C[1], C[2], C[3]};
  Vc[o] = (float4){V[0], V[1], V[2], V[3]};
}

// ---------------- scan pass 2: apply with inline carry-in prefix ----------------
__global__ __launch_bounds__(256) void scan_apply_kernel(
    const uint32_t* __restrict__ cv, const float4* __restrict__ Cc,
    const float4* __restrict__ Vc, const float* __restrict__ h0,
    float4* __restrict__ out) {
  const int tid = threadIdx.x;
  const int nc = blockIdx.x, b = blockIdx.y;
  const uint4* cv4 = (const uint4*)cv;

  // Carry-in: H = g(h0), then compose chunk states 0..nc-1 (small, L2-hot).
  float Hr[4];
  #pragma unroll
  for (int j = 0; j < 4; j++) Hr[j] = gfun(h0[(size_t)b * H_ + tid * 4 + j]);
  #pragma unroll 4
  for (int j = 0; j < nc; j++) {
    size_t idx = (size_t)(b * NC_ + j) * (H_ / 4) + tid;
    float4 Cq = Cc[idx], Vq = Vc[idx];
    Hr[0] = Cq.x * Hr[0] + Vq.x;
    Hr[1] = Cq.y * Hr[1] + Vq.y;
    Hr[2] = Cq.z * Hr[2] + Vq.z;
    Hr[3] = Cq.w * Hr[3] + Vq.w;
  }

  size_t base = (size_t)(b * S_ + nc * L_) * (H_ / 4) + tid;
  #pragma unroll 4
  for (int t = 0; t < L_; t++) {
    size_t idx = base + (size_t)t * (H_ / 4);
    uint4 w = cv4[idx];
    float c, v;
    unpack_cv(w.x, c, v); Hr[0] = c * Hr[0] + v;
    unpack_cv(w.y, c, v); Hr[1] = c * Hr[1] + v;
    unpack_cv(w.z, c, v); Hr[2] = c * Hr[2] + v;
    unpack_cv(w.w, c, v); Hr[3] = c * Hr[3] + v;
    out[idx] = (float4){Hr[0], Hr[1], Hr[2], Hr[3]};
  }
}

extern "C" void kernel_launch(void* const* d_in, const int* in_sizes, int n_in,
                              void* d_out, int out_size, void* d_ws, size_t ws_size,
                              hipStream_t stream) {
  const float* x  = (const float*)d_in[0];
  const float* h0 = (const float*)d_in[1];
  const float* Wz = (const float*)d_in[2];
  const float* bz = (const float*)d_in[3];
  const float* Wh = (const float*)d_in[4];
  const float* bh = (const float*)d_in[5];
  float* out = (float*)d_out;

  // Workspace layout (~202 MB): xb is dead after the GEMM; scan chunk-state
  // buffers alias its region.
  char* ws = (char*)d_ws;
  uint16_t* xb  = (uint16_t*)ws; ws += (size_t)M_ * D_ * 2;      // 64 MB
  uint16_t* Wcb = (uint16_t*)ws; ws += (size_t)NT_ * D_ * 2;     // 4 MB
  uint32_t* cvb = (uint32_t*)ws; ws += (size_t)M_ * H_ * 4;      // 134 MB
  char* alias = (char*)xb;
  float* Cc  = (float*)alias; alias += (size_t)B_ * NC_ * H_ * 4;  // 2 MB
  float* Vc  = (float*)alias; alias += (size_t)B_ * NC_ * H_ * 4;  // 2 MB

  // 1) convert x -> bf16; interleave Wz/Wh -> Wc (2048x1024 bf16)
  cvt_all_kernel<<<dim3(2048), 256, 0, stream>>>(x, Wz, Wh, xb, Wcb);

  // 2) 256x256-tile phase-split GEMM + activation -> packed (c,v) fp16 pairs
  fused_gemm_kernel<<<dim3((NT_ / 256) * (M_ / 256)), 512, 0, stream>>>(
      xb, Wcb, bz, bh, cvb);

  // 3-4) chunked linear scan
  scan_chunk_kernel<<<dim3(NC_, B_), 256, 0, stream>>>(cvb, (float4*)Cc, (float4*)Vc);
  scan_apply_kernel<<<dim3(NC_, B_), 256, 0, stream>>>(
      cvb, (const float4*)Cc, (const float4*)Vc, h0, (float4*)out);
}